// Round 7
// baseline (427.514 us; speedup 1.0000x reference)
//
#include <hip/hip_runtime.h>
#include <math.h>

#define NSEQ 2048
#define NPOS 4095   // 2*NSEQ-1
#define NH   8

typedef _Float16 f16;
typedef f16 f16x8 __attribute__((ext_vector_type(8)));
typedef f16 f16x4 __attribute__((ext_vector_type(4)));
typedef float f32x4 __attribute__((ext_vector_type(4)));

#define MFMA16(a,b,c) __builtin_amdgcn_mfma_f32_16x16x32_f16(a,b,c,0,0,0)

__device__ __forceinline__ f16x8 cvt8(float4 a, float4 b) {
  f16x8 r = {(f16)a.x, (f16)a.y, (f16)a.z, (f16)a.w,
             (f16)b.x, (f16)b.y, (f16)b.z, (f16)b.w};
  return r;
}

// ---------------- positional embedding pos[NPOS][192], one lane per (t,f) ----
__global__ __launch_bounds__(256) void pos_embed_k(float* __restrict__ pos) {
  int t = blockIdx.x * 8 + (threadIdx.x >> 5);
  int f = threadIdx.x & 31;
  if (t >= NPOS) return;
  float dist = (float)(t - (NSEQ - 1));
  float ad = fabsf(dist);
  float sgn = (dist > 0.f) ? 1.f : ((dist < 0.f) ? -1.f : 0.f);
  double mean = 64.0 * (double)(f + 1);       // linspace(64,2048,32)
  double conc = (mean / 32.0) * (mean / 32.0);
  double rate = mean / 1024.0;
  double p = 0.0;
  if (ad > 0.f) {
    double lu = (conc - 1.0) * log((double)ad) - rate * (double)ad;
    double ln = lgamma(conc) - conc * log(rate);
    p = exp(lu - ln);
  }
  float pf = (float)p + 1e-8f;
  float gmax = pf;
  #pragma unroll
  for (int mk = 1; mk <= 16; mk <<= 1) gmax = fmaxf(gmax, __shfl_xor(gmax, mk));
  float fg = pf / gmax;
  float hl = exp2f(3.f + 8.f * (float)f * (1.f / 31.f));
  float fe = exp2f(-ad / hl);
  float cw = exp2f((float)(f + 1)) - 1.f;
  float fc = (cw > ad) ? 1.f : 0.f;
  float* row = pos + (size_t)t * 192;
  row[f]       = fe;       row[32 + f]  = fc;       row[64 + f]  = fg;
  row[96 + f]  = sgn * fe; row[128 + f] = sgn * fc; row[160 + f] = sgn * fg;
}

// ---------------- relq = pos @ Wrel -> f16 [h][NPOS][64] (64x64 tiles) ------
__global__ __launch_bounds__(256) void relq_k(
    const float* __restrict__ A, const float* __restrict__ W, f16* __restrict__ relq)
{
  __shared__ f16 As[64][56];
  __shared__ f16 Bs[64][56];
  int tid = threadIdx.x, w = tid >> 6, lane = tid & 63, lr = lane >> 4, lc = lane & 15;
  int m0 = blockIdx.y * 64, n0 = blockIdx.x * 64;
  int ar = tid >> 2, ac = (tid & 3) * 8;
  int bk = tid >> 3, bn = (tid & 7) * 8;
  f32x4 acc[4] = {};
  for (int k0 = 0; k0 < 192; k0 += 32) {
    float4 a0 = make_float4(0.f,0.f,0.f,0.f), a1 = a0;
    if (m0 + ar < NPOS) {
      const float* ap = &A[(size_t)(m0 + ar) * 192 + k0 + ac];
      a0 = *(const float4*)ap; a1 = *(const float4*)(ap + 4);
    }
    *(f16x8*)&As[ar][ac] = cvt8(a0, a1);
    const float* bp = &W[(size_t)(k0 + bk) * 512 + n0 + bn];
    float4 b0 = *(const float4*)bp, b1 = *(const float4*)(bp + 4);
    f16 bv[8] = {(f16)b0.x,(f16)b0.y,(f16)b0.z,(f16)b0.w,(f16)b1.x,(f16)b1.y,(f16)b1.z,(f16)b1.w};
    #pragma unroll
    for (int tt = 0; tt < 8; tt++) { int t = (tt + bk) & 7; Bs[bn + t][bk] = bv[t]; }
    __syncthreads();
    f16x8 af = *(const f16x8*)&As[16*w + lc][8*lr];
    #pragma unroll
    for (int nt = 0; nt < 4; nt++) {
      f16x8 bf = *(const f16x8*)&Bs[16*nt + lc][8*lr];
      acc[nt] = MFMA16(af, bf, acc[nt]);
    }
    __syncthreads();
  }
  #pragma unroll
  for (int nt = 0; nt < 4; nt++)
    #pragma unroll
    for (int r = 0; r < 4; r++) {
      int m = m0 + 16*w + 4*lr + r;
      if (m >= NPOS) continue;
      int nn = n0 + 16*nt + lc;
      relq[((size_t)(nn >> 6) * NPOS + m) * 64 + (nn & 63)] = (f16)acc[nt][r];
    }
}

// ---------------- input projections, 128x128 tile: A[4096,KD] x (W1|W2) -----
template<int KD, bool SC1>
__global__ __launch_bounds__(256) void projx_k(
    const float* __restrict__ A, const float* __restrict__ W1, const float* __restrict__ W2,
    f16* __restrict__ O1, f16* __restrict__ O2, const float* __restrict__ rpb)
{
  __shared__ f16 As[128][40];
  __shared__ f16 Bs[128][40];
  int tid = threadIdx.x, w = tid >> 6, lane = tid & 63, lr = lane >> 4, lc = lane & 15;
  int wm = w >> 1, wn = w & 1;
  int m0 = blockIdx.y * 128, n0g = blockIdx.x * 128;
  bool first = (n0g < 512);
  const float* W = first ? W1 : W2;
  f16* O = first ? O1 : O2;
  int n0 = n0g & 511;
  int ar = tid >> 1, ac = (tid & 1) * 16;
  int bk = tid >> 3, bn = (tid & 7) * 16;
  f32x4 acc[4][4] = {};
  for (int k0 = 0; k0 < KD; k0 += 32) {
    const float* ap = &A[(size_t)(m0 + ar) * KD + k0 + ac];
    *(f16x8*)&As[ar][ac]     = cvt8(*(const float4*)ap, *(const float4*)(ap + 4));
    *(f16x8*)&As[ar][ac + 8] = cvt8(*(const float4*)(ap + 8), *(const float4*)(ap + 12));
    const float* bp = &W[(size_t)(k0 + bk) * 512 + n0 + bn];
    f16 bv[16];
    #pragma unroll
    for (int u = 0; u < 4; u++) {
      float4 b = *(const float4*)(bp + u * 4);
      bv[4*u+0] = (f16)b.x; bv[4*u+1] = (f16)b.y; bv[4*u+2] = (f16)b.z; bv[4*u+3] = (f16)b.w;
    }
    #pragma unroll
    for (int tt = 0; tt < 16; tt++) { int t = (tt + bk) & 15; Bs[bn + t][bk] = bv[t]; }
    __syncthreads();
    f16x8 af[4], bf[4];
    #pragma unroll
    for (int x = 0; x < 4; x++) af[x] = *(const f16x8*)&As[64*wm + 16*x + lc][8*lr];
    #pragma unroll
    for (int y = 0; y < 4; y++) bf[y] = *(const f16x8*)&Bs[64*wn + 16*y + lc][8*lr];
    #pragma unroll
    for (int x = 0; x < 4; x++)
      #pragma unroll
      for (int y = 0; y < 4; y++) acc[x][y] = MFMA16(af[x], bf[y], acc[x][y]);
    __syncthreads();
  }
  #pragma unroll
  for (int x = 0; x < 4; x++)
    #pragma unroll
    for (int y = 0; y < 4; y++)
      #pragma unroll
      for (int r = 0; r < 4; r++) {
        int m = m0 + 64*wm + 16*x + 4*lr + r;
        int nn = n0 + 64*wn + 16*y + lc;
        float vv = acc[x][y][r];
        if (SC1 && first) vv = vv * 0.125f + rpb[nn];
        O[(((size_t)((m >> 11) * NH + (nn >> 6))) * NSEQ + (m & (NSEQ - 1))) * 64 + (nn & 63)] = (f16)vv;
      }
}

// ---------------- output projections, 128x128 tile ----------------
__global__ __launch_bounds__(256) void outproj_k(
    const f16* __restrict__ o1, const f16* __restrict__ o2,
    const float* __restrict__ Wo1, const float* __restrict__ Wo2,
    const float* __restrict__ bo1, const float* __restrict__ bo2,
    float* __restrict__ out)
{
  __shared__ f16 As[128][40];
  __shared__ f16 Bs[128][40];
  int by = blockIdx.y;
  bool first = (by < 32);
  const f16* A = first ? o1 : o2;
  const float* W = first ? Wo1 : Wo2;
  const float* bias = first ? bo1 : bo2;
  float* O = out + (first ? 0 : (size_t)4096 * 1024);
  int tid = threadIdx.x, w = tid >> 6, lane = tid & 63, lr = lane >> 4, lc = lane & 15;
  int wm = w >> 1, wn = w & 1;
  int m0 = (by & 31) * 128, n0 = blockIdx.x * 128;
  int ar = tid >> 1, ac = (tid & 1) * 16;
  int bk = tid >> 3, bn = (tid & 7) * 16;
  f32x4 acc[4][4] = {};
  for (int k0 = 0; k0 < 512; k0 += 32) {
    const f16* ap = &A[(size_t)(m0 + ar) * 512 + k0 + ac];
    *(f16x8*)&As[ar][ac]     = *(const f16x8*)ap;
    *(f16x8*)&As[ar][ac + 8] = *(const f16x8*)(ap + 8);
    const float* bp = &W[(size_t)(k0 + bk) * 1024 + n0 + bn];
    f16 bv[16];
    #pragma unroll
    for (int u = 0; u < 4; u++) {
      float4 b = *(const float4*)(bp + u * 4);
      bv[4*u+0] = (f16)b.x; bv[4*u+1] = (f16)b.y; bv[4*u+2] = (f16)b.z; bv[4*u+3] = (f16)b.w;
    }
    #pragma unroll
    for (int tt = 0; tt < 16; tt++) { int t = (tt + bk) & 15; Bs[bn + t][bk] = bv[t]; }
    __syncthreads();
    f16x8 af[4], bf[4];
    #pragma unroll
    for (int x = 0; x < 4; x++) af[x] = *(const f16x8*)&As[64*wm + 16*x + lc][8*lr];
    #pragma unroll
    for (int y = 0; y < 4; y++) bf[y] = *(const f16x8*)&Bs[64*wn + 16*y + lc][8*lr];
    #pragma unroll
    for (int x = 0; x < 4; x++)
      #pragma unroll
      for (int y = 0; y < 4; y++) acc[x][y] = MFMA16(af[x], bf[y], acc[x][y]);
    __syncthreads();
  }
  #pragma unroll
  for (int x = 0; x < 4; x++)
    #pragma unroll
    for (int y = 0; y < 4; y++)
      #pragma unroll
      for (int r = 0; r < 4; r++) {
        int m = m0 + 64*wm + 16*x + 4*lr + r;
        int n = n0 + 64*wn + 16*y + lc;
        O[(size_t)m * 1024 + n] = acc[x][y][r] + bias[n];
      }
}

// ---------------- fused logits + online softmax + out1 PV ----------------
// l[i,j] = q[i]·kb[j] + G[j, i-j+63];  G[j,n] = kb[j]·relq[nbase+n]
// Sliding-window R ring: panel p covers rel rows [base0-64p, base0-64p+64),
// base0 = i0+1984; tile jt needs panels {jt (n in [0,64)), jt-1 (n in [64,128))}.
// LDS (54400 B): Qs[64][72]@0 (G2[64][68] overlay), KBs[64][72]@9216 (Pw per-wave
// overlay), Rs2[2][64][72]@18432, Vs[64][72]@36864, m_lds[32][65] f32 @46080.
__global__ __launch_bounds__(256) void attn_k(
    const f16* __restrict__ q, const f16* __restrict__ kb,
    const f16* __restrict__ relq, const f16* __restrict__ v2,
    f16* __restrict__ attn, float* __restrict__ fac,
    f16* __restrict__ o1acc, int bh0)
{
  __shared__ char smem[54400];
  f16 (*Qs)[72]  = (f16(*)[72])smem;
  f16 (*KBs)[72] = (f16(*)[72])(smem + 9216);
  f16 (*Rs0)[72] = (f16(*)[72])(smem + 18432);
  f16 (*Rs1)[72] = (f16(*)[72])(smem + 27648);
  f16 (*Vs)[72]  = (f16(*)[72])(smem + 36864);
  f16 (*G2)[68]  = (f16(*)[68])smem;                  // overlay Qs
  float (*m_lds)[65] = (float(*)[65])(smem + 46080);
  int z = blockIdx.y, bh = bh0 + z, b = bh >> 3, h = bh & 7;
  int i0 = blockIdx.x * 64;
  int tid = threadIdx.x, w = tid >> 6, lane = tid & 63;
  int lr = lane >> 4, lc = lane & 15;
  f16 (*Pw)[72] = (f16(*)[72])(smem + 9216 + w * 2304);  // per-wave [16][72]
  int base0 = i0 + 1984;   // (NSEQ-1) + i0 - 63

  {
    int row = tid >> 2, c0 = (tid & 3) * 16;
    const f16* qp = q + ((size_t)bh * NSEQ + i0 + row) * 64 + c0;
    *(f16x8*)&Qs[row][c0]     = *(const f16x8*)qp;
    *(f16x8*)&Qs[row][c0 + 8] = *(const f16x8*)(qp + 8);
    // prologue: panel -1 -> slot 1
    int rr = tid >> 2, rd = (tid & 3) * 16;
    const f16* rp = relq + ((size_t)h * NPOS + base0 + 64 + rr) * 64 + rd;
    *(f16x8*)&Rs1[rr][rd]     = *(const f16x8*)rp;
    *(f16x8*)&Rs1[rr][rd + 8] = *(const f16x8*)(rp + 8);
  }
  __syncthreads();
  f16x8 qa0 = *(const f16x8*)&Qs[16*w + lc][8*lr];
  f16x8 qa1 = *(const f16x8*)&Qs[16*w + lc][32 + 8*lr];

  float m_run[4], ssum[4];
  f32x4 o1a[4] = {};
  #pragma unroll
  for (int r = 0; r < 4; r++) { m_run[r] = -1e30f; ssum[r] = 0.f; }

  for (int jt = 0; jt < 32; jt++) {
    int j0 = jt * 64;
    f16 (*RsA)[72] = (jt & 1) ? Rs1 : Rs0;   // panel jt: n in [0,64)
    f16 (*RsB)[72] = (jt & 1) ? Rs0 : Rs1;   // panel jt-1: n in [64,128)
    {
      int row = tid >> 2, c0 = (tid & 3) * 16;
      const f16* kp = kb + ((size_t)bh * NSEQ + j0 + row) * 64 + c0;
      *(f16x8*)&KBs[row][c0]     = *(const f16x8*)kp;
      *(f16x8*)&KBs[row][c0 + 8] = *(const f16x8*)(kp + 8);
      const f16* vp = v2 + ((size_t)bh * NSEQ + j0 + row) * 64 + c0;
      f16x8 u0 = *(const f16x8*)vp, u1 = *(const f16x8*)(vp + 8);
      #pragma unroll
      for (int tt = 0; tt < 8; tt++) {
        int t = (tt + row) & 7;
        Vs[c0 + t][row] = u0[t];
        Vs[c0 + 8 + t][row] = u1[t];
      }
      // stage panel jt -> RsA (rows base0-64*jt .. +64)
      const f16* rp = relq + ((size_t)h * NPOS + base0 - 64*jt + row) * 64 + c0;
      *(f16x8*)&RsA[row][c0]     = *(const f16x8*)rp;
      *(f16x8*)&RsA[row][c0 + 8] = *(const f16x8*)(rp + 8);
    }
    __syncthreads();   // s1: staging visible
    f32x4 cacc[4];
    f16x8 ka0 = {}, ka1 = {};
    #pragma unroll
    for (int y = 0; y < 4; y++) {
      f16x8 b0 = *(const f16x8*)&KBs[16*y + lc][8*lr];
      f16x8 b1 = *(const f16x8*)&KBs[16*y + lc][32 + 8*lr];
      f32x4 t = {};
      t = MFMA16(qa0, b0, t);
      t = MFMA16(qa1, b1, t);
      cacc[y] = t;
      if (y == w) { ka0 = b0; ka1 = b1; }
    }
    #pragma unroll
    for (int g = 0; g < 8; g++) {
      const f16* r0p = (g < 4) ? &RsA[16*g + lc][8*lr]        : &RsB[16*(g-4) + lc][8*lr];
      const f16* r1p = (g < 4) ? &RsA[16*g + lc][32 + 8*lr]   : &RsB[16*(g-4) + lc][32 + 8*lr];
      f32x4 ga = {};
      ga = MFMA16(ka0, *(const f16x8*)r0p, ga);
      ga = MFMA16(ka1, *(const f16x8*)r1p, ga);
      int jj = 16*w + 4*lr;
      #pragma unroll
      for (int r = 0; r < 4; r++) {
        int ii = 16*g + lc + jj + r - 63;   // i = n + j - 63
        if ((unsigned)ii < 64u) G2[jj + r][ii] = (f16)ga[r];
      }
    }
    __syncthreads();   // s2: G2 complete; KBs frag reads done -> Pw overlay safe
    float l[4][4];
    #pragma unroll
    for (int y = 0; y < 4; y++) {
      f16x4 gv = *(const f16x4*)&G2[16*y + lc][16*w + 4*lr];
      #pragma unroll
      for (int r = 0; r < 4; r++) l[y][r] = cacc[y][r] + (float)gv[r];
    }
    #pragma unroll
    for (int r = 0; r < 4; r++) {
      float tm = fmaxf(fmaxf(l[0][r], l[1][r]), fmaxf(l[2][r], l[3][r]));
      #pragma unroll
      for (int mk = 1; mk <= 8; mk <<= 1) tm = fmaxf(tm, __shfl_xor(tm, mk));
      if (tm > m_run[r]) {
        float sc = __expf(m_run[r] - tm);
        ssum[r] *= sc;
        #pragma unroll
        for (int nt = 0; nt < 4; nt++) o1a[nt][r] *= sc;
        m_run[r] = tm;
      }
      float mnew = m_run[r];
      float ps = 0.f;
      #pragma unroll
      for (int y = 0; y < 4; y++) {
        float p = __expf(l[y][r] - mnew);
        ps += p;
        Pw[4*lr + r][16*y + lc] = (f16)p;
      }
      ssum[r] += ps;
      if (lc == 0) m_lds[jt][16*w + 4*lr + r] = mnew;
    }
    // no barrier: Pw/m_lds are per-wave written & per-wave read (lgkmcnt only)
    {
      int prow = lane >> 2, pc0 = (lane & 3) * 16;
      f16* ap = attn + ((size_t)z * NSEQ + i0 + 16*w + prow) * NSEQ + j0 + pc0;
      *(f16x8*)ap       = *(const f16x8*)&Pw[prow][pc0];
      *(f16x8*)(ap + 8) = *(const f16x8*)&Pw[prow][pc0 + 8];
    }
    {
      f16x8 pa0 = *(const f16x8*)&Pw[lc][8*lr];
      f16x8 pa1 = *(const f16x8*)&Pw[lc][32 + 8*lr];
      #pragma unroll
      for (int nt = 0; nt < 4; nt++) {
        f16x8 vf0 = *(const f16x8*)&Vs[16*nt + lc][8*lr];
        f16x8 vf1 = *(const f16x8*)&Vs[16*nt + lc][32 + 8*lr];
        o1a[nt] = MFMA16(pa0, vf0, o1a[nt]);
        o1a[nt] = MFMA16(pa1, vf1, o1a[nt]);
      }
    }
    __syncthreads();   // s4: all reads of KBs/Pw/G2/Vs/Rs done -> restage ok
  }
  // epilogue: reduce s per row; write fac (for pv2) and out1
  float invs[4];
  #pragma unroll
  for (int r = 0; r < 4; r++) {
    float s = ssum[r];
    #pragma unroll
    for (int mk = 1; mk <= 8; mk <<= 1) s += __shfl_xor(s, mk);
    invs[r] = 1.f / s;
    int il = 16*w + 4*lr + r;
    float mf = m_run[r];
    #pragma unroll
    for (int jtb = 0; jtb < 2; jtb++) {
      int jt = jtb * 16 + lc;
      float fv = __expf(m_lds[jt][il] - mf) * invs[r];
      fac[((size_t)z * NSEQ + i0 + il) * 32 + jt] = fv;
    }
  }
  #pragma unroll
  for (int nt = 0; nt < 4; nt++)
    #pragma unroll
    for (int r = 0; r < 4; r++) {
      int row = i0 + 16*w + 4*lr + r;
      o1acc[((size_t)b * NSEQ + row) * 512 + h * 64 + 16*nt + lc] = (f16)(o1a[nt][r] * invs[r]);
    }
}

// ---------------- pv2, 128-j tile: out2[j,d] = sum_i (fac*P)[i,j] v1[i,d] ----
__global__ __launch_bounds__(256) void pv2_k(const f16* __restrict__ attn,
    const f16* __restrict__ v, const float* __restrict__ fac,
    f16* __restrict__ oacc, int bh0)
{
  __shared__ f16 As[128][40];   // P^T: [j][i-k]
  __shared__ f16 Vs[64][40];    // v1^T: [d][i-k]
  int z = blockIdx.y, bh = bh0 + z, b = bh >> 3, h = bh & 7;
  int r0 = blockIdx.x * 128;
  int tid = threadIdx.x, w = tid >> 6, lane = tid & 63;
  int lr = lane >> 4, lc = lane & 15;
  int wm = w >> 1, wn = w & 1;
  f32x4 acc[4][2] = {};
  int kk = tid >> 3, c0 = (tid & 7) * 16;
  int jt_off = (r0 >> 6) + ((tid & 7) >> 2);
  int d0 = (tid & 7) * 8;
  for (int k0 = 0; k0 < NSEQ; k0 += 32) {
    {
      const f16* ap = &attn[((size_t)z * NSEQ + k0 + kk) * NSEQ + r0 + c0];
      f16x8 a0 = *(const f16x8*)ap, a1 = *(const f16x8*)(ap + 8);
      f16 sc = (f16)fac[((size_t)z * NSEQ + k0 + kk) * 32 + jt_off];
      #pragma unroll
      for (int tt = 0; tt < 8; tt++) {
        int t = (tt + kk) & 7;
        As[c0 + t][kk] = a0[t] * sc;
        As[c0 + 8 + t][kk] = a1[t] * sc;
      }
      f16x8 vv = *(const f16x8*)&v[((size_t)bh * NSEQ + k0 + kk) * 64 + d0];
      #pragma unroll
      for (int tt = 0; tt < 8; tt++) { int t = (tt + kk) & 7; Vs[d0 + t][kk] = vv[t]; }
    }
    __syncthreads();
    f16x8 af[4], bf[2];
    #pragma unroll
    for (int x = 0; x < 4; x++) af[x] = *(const f16x8*)&As[64*wm + 16*x + lc][8*lr];
    #pragma unroll
    for (int y = 0; y < 2; y++) bf[y] = *(const f16x8*)&Vs[32*wn + 16*y + lc][8*lr];
    #pragma unroll
    for (int x = 0; x < 4; x++)
      #pragma unroll
      for (int y = 0; y < 2; y++) acc[x][y] = MFMA16(af[x], bf[y], acc[x][y]);
    __syncthreads();
  }
  #pragma unroll
  for (int x = 0; x < 4; x++)
    #pragma unroll
    for (int y = 0; y < 2; y++)
      #pragma unroll
      for (int r = 0; r < 4; r++) {
        int row = r0 + 64*wm + 16*x + 4*lr + r;
        int d = 32*wn + 16*y + lc;
        oacc[((size_t)b * NSEQ + row) * 512 + h * 64 + d] = (f16)acc[x][y][r];
      }
}

extern "C" void kernel_launch(void* const* d_in, const int* in_sizes, int n_in,
                              void* d_out, int out_size, void* d_ws, size_t ws_size,
                              hipStream_t stream) {
  const float* x1   = (const float*)d_in[0];
  const float* x2   = (const float*)d_in[1];
  const float* Wq   = (const float*)d_in[2];
  const float* Wk   = (const float*)d_in[3];
  const float* Wv1  = (const float*)d_in[4];
  const float* Wv2  = (const float*)d_in[5];
  const float* Wrel = (const float*)d_in[6];
  const float* rpb  = (const float*)d_in[7];
  const float* Wo1  = (const float*)d_in[8];
  const float* bo1  = (const float*)d_in[9];
  const float* Wo2  = (const float*)d_in[10];
  const float* bo2  = (const float*)d_in[11];
  float* out = (float*)d_out;

  char* base = (char*)d_ws;
  size_t off = 0;
  auto alloc = [&](size_t bytes) -> void* {
    void* p = base + off; off += (bytes + 255) & ~(size_t)255; return p;
  };
  float* pos   = (float*)alloc((size_t)NPOS * 192 * 4);
  f16*   relq  = (f16*)  alloc((size_t)NH * NPOS * 64 * 2);
  f16*   qh    = (f16*)  alloc((size_t)16 * NSEQ * 64 * 2);
  f16*   kbh   = (f16*)  alloc((size_t)16 * NSEQ * 64 * 2);
  f16*   v1h   = (f16*)  alloc((size_t)16 * NSEQ * 64 * 2);
  f16*   v2h   = (f16*)  alloc((size_t)16 * NSEQ * 64 * 2);
  f16*   o1acc = (f16*)  alloc((size_t)2 * NSEQ * 512 * 2);
  f16*   o2acc = (f16*)  alloc((size_t)2 * NSEQ * 512 * 2);
  size_t baseB = off;

  int chunk = 1;
  for (int c = 16; c >= 1; c >>= 1) {
    size_t needB = baseB + (size_t)c * (NSEQ * (size_t)NSEQ * 2 + NSEQ * 32 * 4);
    if (needB <= ws_size) { chunk = c; break; }
  }
  f16*   attn = (f16*)(base + baseB);
  float* fac  = (float*)(base + baseB + (size_t)chunk * NSEQ * NSEQ * 2);

  pos_embed_k<<<(NPOS + 7) / 8, 256, 0, stream>>>(pos);
  relq_k<<<dim3(8, 64), 256, 0, stream>>>(pos, Wrel, relq);
  projx_k<1024, false><<<dim3(8, 32), 256, 0, stream>>>(x1, Wq, Wv1, qh, v1h, nullptr);
  projx_k<512,  true ><<<dim3(8, 32), 256, 0, stream>>>(x2, Wk, Wv2, kbh, v2h, rpb);

  for (int bh0 = 0; bh0 < 16; bh0 += chunk) {
    attn_k<<<dim3(32, chunk), 256, 0, stream>>>(qh, kbh, relq, v2h, attn, fac, o1acc, bh0);
    pv2_k<<<dim3(16, chunk), 256, 0, stream>>>(attn, v1h, fac, o2acc, bh0);
  }

  outproj_k<<<dim3(8, 64), 256, 0, stream>>>(o1acc, o2acc, Wo1, Wo2, bo1, bo2, out);
}

// Round 8
// 342.820 us; speedup vs baseline: 1.2471x; 1.2471x over previous
//
#include <hip/hip_runtime.h>
#include <math.h>

#define NSEQ 2048
#define NPOS 4095   // 2*NSEQ-1
#define NH   8

typedef _Float16 f16;
typedef f16 f16x8 __attribute__((ext_vector_type(8)));
typedef f16 f16x4 __attribute__((ext_vector_type(4)));
typedef float f32x4 __attribute__((ext_vector_type(4)));

#define MFMA16(a,b,c) __builtin_amdgcn_mfma_f32_16x16x32_f16(a,b,c,0,0,0)

__device__ __forceinline__ f16x8 cvt8(float4 a, float4 b) {
  f16x8 r = {(f16)a.x, (f16)a.y, (f16)a.z, (f16)a.w,
             (f16)b.x, (f16)b.y, (f16)b.z, (f16)b.w};
  return r;
}

// ---------------- positional embedding pos[NPOS][192], one lane per (t,f) ----
__global__ __launch_bounds__(256) void pos_embed_k(float* __restrict__ pos) {
  int t = blockIdx.x * 8 + (threadIdx.x >> 5);
  int f = threadIdx.x & 31;
  if (t >= NPOS) return;
  float dist = (float)(t - (NSEQ - 1));
  float ad = fabsf(dist);
  float sgn = (dist > 0.f) ? 1.f : ((dist < 0.f) ? -1.f : 0.f);
  double mean = 64.0 * (double)(f + 1);       // linspace(64,2048,32)
  double conc = (mean / 32.0) * (mean / 32.0);
  double rate = mean / 1024.0;
  double p = 0.0;
  if (ad > 0.f) {
    double lu = (conc - 1.0) * log((double)ad) - rate * (double)ad;
    double ln = lgamma(conc) - conc * log(rate);
    p = exp(lu - ln);
  }
  float pf = (float)p + 1e-8f;
  float gmax = pf;
  #pragma unroll
  for (int mk = 1; mk <= 16; mk <<= 1) gmax = fmaxf(gmax, __shfl_xor(gmax, mk));
  float fg = pf / gmax;
  float hl = exp2f(3.f + 8.f * (float)f * (1.f / 31.f));
  float fe = exp2f(-ad / hl);
  float cw = exp2f((float)(f + 1)) - 1.f;
  float fc = (cw > ad) ? 1.f : 0.f;
  float* row = pos + (size_t)t * 192;
  row[f]       = fe;       row[32 + f]  = fc;       row[64 + f]  = fg;
  row[96 + f]  = sgn * fe; row[128 + f] = sgn * fc; row[160 + f] = sgn * fg;
}

// ---------------- relq = pos @ Wrel -> f16 [h][NPOS][64] (64x64 tiles) ------
__global__ __launch_bounds__(256) void relq_k(
    const float* __restrict__ A, const float* __restrict__ W, f16* __restrict__ relq)
{
  __shared__ f16 As[64][56];
  __shared__ f16 Bs[64][56];
  int tid = threadIdx.x, w = tid >> 6, lane = tid & 63, lr = lane >> 4, lc = lane & 15;
  int m0 = blockIdx.y * 64, n0 = blockIdx.x * 64;
  int ar = tid >> 2, ac = (tid & 3) * 8;
  int bk = tid >> 3, bn = (tid & 7) * 8;
  f32x4 acc[4] = {};
  for (int k0 = 0; k0 < 192; k0 += 32) {
    float4 a0 = make_float4(0.f,0.f,0.f,0.f), a1 = a0;
    if (m0 + ar < NPOS) {
      const float* ap = &A[(size_t)(m0 + ar) * 192 + k0 + ac];
      a0 = *(const float4*)ap; a1 = *(const float4*)(ap + 4);
    }
    *(f16x8*)&As[ar][ac] = cvt8(a0, a1);
    const float* bp = &W[(size_t)(k0 + bk) * 512 + n0 + bn];
    float4 b0 = *(const float4*)bp, b1 = *(const float4*)(bp + 4);
    f16 bv[8] = {(f16)b0.x,(f16)b0.y,(f16)b0.z,(f16)b0.w,(f16)b1.x,(f16)b1.y,(f16)b1.z,(f16)b1.w};
    #pragma unroll
    for (int tt = 0; tt < 8; tt++) { int t = (tt + bk) & 7; Bs[bn + t][bk] = bv[t]; }
    __syncthreads();
    f16x8 af = *(const f16x8*)&As[16*w + lc][8*lr];
    #pragma unroll
    for (int nt = 0; nt < 4; nt++) {
      f16x8 bf = *(const f16x8*)&Bs[16*nt + lc][8*lr];
      acc[nt] = MFMA16(af, bf, acc[nt]);
    }
    __syncthreads();
  }
  #pragma unroll
  for (int nt = 0; nt < 4; nt++)
    #pragma unroll
    for (int r = 0; r < 4; r++) {
      int m = m0 + 16*w + 4*lr + r;
      if (m >= NPOS) continue;
      int nn = n0 + 16*nt + lc;
      relq[((size_t)(nn >> 6) * NPOS + m) * 64 + (nn & 63)] = (f16)acc[nt][r];
    }
}

// ---------------- input projections (64x64 tile): A[4096,KD] x (W1|W2) -----
// first half  -> O1 normal head-split [bh][row][64] (optionally *0.125+rpb)
// second half -> O2t TRANSPOSED [bh][d][2048] (f16x4-packed stores)
template<int KD, bool SC1>
__global__ __launch_bounds__(256) void projx_k(
    const float* __restrict__ A, const float* __restrict__ W1, const float* __restrict__ W2,
    f16* __restrict__ O1, f16* __restrict__ O2t, const float* __restrict__ rpb)
{
  __shared__ f16 As[64][56];
  __shared__ f16 Bs[64][56];
  int tid = threadIdx.x, w = tid >> 6, lane = tid & 63, lr = lane >> 4, lc = lane & 15;
  int m0 = blockIdx.y * 64, n0g = blockIdx.x * 64;
  bool first = (n0g < 512);
  const float* W = first ? W1 : W2;
  int n0 = n0g & 511;
  int ar = tid >> 2, ac = (tid & 3) * 8;
  int bk = tid >> 3, bn = (tid & 7) * 8;
  f32x4 acc[4] = {};
  for (int k0 = 0; k0 < KD; k0 += 32) {
    const float* ap = &A[(size_t)(m0 + ar) * KD + k0 + ac];
    *(f16x8*)&As[ar][ac] = cvt8(*(const float4*)ap, *(const float4*)(ap + 4));
    const float* bp = &W[(size_t)(k0 + bk) * 512 + n0 + bn];
    float4 b0 = *(const float4*)bp, b1 = *(const float4*)(bp + 4);
    f16 bv[8] = {(f16)b0.x,(f16)b0.y,(f16)b0.z,(f16)b0.w,(f16)b1.x,(f16)b1.y,(f16)b1.z,(f16)b1.w};
    #pragma unroll
    for (int tt = 0; tt < 8; tt++) { int t = (tt + bk) & 7; Bs[bn + t][bk] = bv[t]; }
    __syncthreads();
    f16x8 af = *(const f16x8*)&As[16*w + lc][8*lr];
    #pragma unroll
    for (int nt = 0; nt < 4; nt++) {
      f16x8 bf = *(const f16x8*)&Bs[16*nt + lc][8*lr];
      acc[nt] = MFMA16(af, bf, acc[nt]);
    }
    __syncthreads();
  }
  if (first) {
    #pragma unroll
    for (int nt = 0; nt < 4; nt++)
      #pragma unroll
      for (int r = 0; r < 4; r++) {
        int m = m0 + 16*w + 4*lr + r;
        int nn = n0 + 16*nt + lc;
        float vv = acc[nt][r];
        if (SC1) vv = vv * 0.125f + rpb[nn];
        O1[(((size_t)((m >> 11) * NH + (nn >> 6))) * NSEQ + (m & (NSEQ - 1))) * 64 + (nn & 63)] = (f16)vv;
      }
  } else {
    int mb = m0 + 16*w + 4*lr;
    #pragma unroll
    for (int nt = 0; nt < 4; nt++) {
      int nn = n0 + 16*nt + lc;
      f16x4 pk = {(f16)acc[nt][0], (f16)acc[nt][1], (f16)acc[nt][2], (f16)acc[nt][3]};
      *(f16x4*)&O2t[(((size_t)((mb >> 11) * NH + (nn >> 6))) * 64 + (nn & 63)) * NSEQ + (mb & (NSEQ - 1))] = pk;
    }
  }
}

// ---------------- fused output projections (64x64 tile) ----------------
__global__ __launch_bounds__(256) void outproj_k(
    const f16* __restrict__ o1, const f16* __restrict__ o2,
    const float* __restrict__ Wo1, const float* __restrict__ Wo2,
    const float* __restrict__ bo1, const float* __restrict__ bo2,
    float* __restrict__ out)
{
  __shared__ f16 As[64][56];
  __shared__ f16 Bs[64][56];
  int by = blockIdx.y;
  bool first = (by < 64);
  const f16* A = first ? o1 : o2;
  const float* W = first ? Wo1 : Wo2;
  const float* bias = first ? bo1 : bo2;
  float* O = out + (first ? 0 : (size_t)4096 * 1024);
  int tid = threadIdx.x, w = tid >> 6, lane = tid & 63, lr = lane >> 4, lc = lane & 15;
  int m0 = (by & 63) * 64, n0 = blockIdx.x * 64;
  int ar = tid >> 2, ac = (tid & 3) * 8;
  int bk = tid >> 3, bn = (tid & 7) * 8;
  f32x4 acc[4] = {};
  for (int k0 = 0; k0 < 512; k0 += 32) {
    *(f16x8*)&As[ar][ac] = *(const f16x8*)&A[(size_t)(m0 + ar) * 512 + k0 + ac];
    const float* bp = &W[(size_t)(k0 + bk) * 1024 + n0 + bn];
    float4 b0 = *(const float4*)bp, b1 = *(const float4*)(bp + 4);
    f16 bv[8] = {(f16)b0.x,(f16)b0.y,(f16)b0.z,(f16)b0.w,(f16)b1.x,(f16)b1.y,(f16)b1.z,(f16)b1.w};
    #pragma unroll
    for (int tt = 0; tt < 8; tt++) { int t = (tt + bk) & 7; Bs[bn + t][bk] = bv[t]; }
    __syncthreads();
    f16x8 af = *(const f16x8*)&As[16*w + lc][8*lr];
    #pragma unroll
    for (int nt = 0; nt < 4; nt++) {
      f16x8 bf = *(const f16x8*)&Bs[16*nt + lc][8*lr];
      acc[nt] = MFMA16(af, bf, acc[nt]);
    }
    __syncthreads();
  }
  #pragma unroll
  for (int nt = 0; nt < 4; nt++)
    #pragma unroll
    for (int r = 0; r < 4; r++) {
      int m = m0 + 16*w + 4*lr + r;
      int n = n0 + 16*nt + lc;
      O[(size_t)m * 1024 + n] = acc[nt][r] + bias[n];
    }
}

// ---------------- fused logits + online softmax + out1 PV ----------------
// l[i,j] = q[i]·kb[j] + G[j, i-j+63];  G[j,n] = kb[j]·relq[nbase+n]
// R ring: panel p = rel rows [base0-64p, +64); tile jt uses panels {jt, jt-1}.
// G-blocks pruned: wave w only computes g in [3-w, 7-w] (others never used).
// Per-jt running max captured in registers (lane lc holds jt=lc / jt=16+lc).
// LDS (46080 B): Qs[64][72]@0 (G2[64][68] overlay), KBs[64][72]@9216 (Pw
// per-wave [16][72] overlay), Rs0/Rs1[64][72]@18432/27648, Vs[64][72]@36864.
__global__ __launch_bounds__(256) void attn_k(
    const f16* __restrict__ q, const f16* __restrict__ kb,
    const f16* __restrict__ relq, const f16* __restrict__ v2t,
    f16* __restrict__ attn, float* __restrict__ fac,
    f16* __restrict__ o1acc, int bh0)
{
  __shared__ char smem[46080];
  f16 (*Qs)[72]  = (f16(*)[72])smem;
  f16 (*KBs)[72] = (f16(*)[72])(smem + 9216);
  f16 (*Rs0)[72] = (f16(*)[72])(smem + 18432);
  f16 (*Rs1)[72] = (f16(*)[72])(smem + 27648);
  f16 (*Vs)[72]  = (f16(*)[72])(smem + 36864);   // [d][j] from v2t
  f16 (*G2)[68]  = (f16(*)[68])smem;             // overlay Qs
  int z = blockIdx.y, bh = bh0 + z, b = bh >> 3, h = bh & 7;
  int i0 = blockIdx.x * 64;
  int tid = threadIdx.x, w = tid >> 6, lane = tid & 63;
  int lr = lane >> 4, lc = lane & 15;
  f16 (*Pw)[72] = (f16(*)[72])(smem + 9216 + w * 2304);  // per-wave [16][72]
  int base0 = i0 + 1984;   // (NSEQ-1) + i0 - 63

  {
    int row = tid >> 2, c0 = (tid & 3) * 16;
    const f16* qp = q + ((size_t)bh * NSEQ + i0 + row) * 64 + c0;
    *(f16x8*)&Qs[row][c0]     = *(const f16x8*)qp;
    *(f16x8*)&Qs[row][c0 + 8] = *(const f16x8*)(qp + 8);
    // prologue: panel -1 -> Rs1
    const f16* rp = relq + ((size_t)h * NPOS + base0 + 64 + row) * 64 + c0;
    *(f16x8*)&Rs1[row][c0]     = *(const f16x8*)rp;
    *(f16x8*)&Rs1[row][c0 + 8] = *(const f16x8*)(rp + 8);
  }
  __syncthreads();
  f16x8 qa0 = *(const f16x8*)&Qs[16*w + lc][8*lr];
  f16x8 qa1 = *(const f16x8*)&Qs[16*w + lc][32 + 8*lr];

  float m_run[4], ssum[4];
  float mreg0[4] = {}, mreg1[4] = {};
  f32x4 o1a[4] = {};
  #pragma unroll
  for (int r = 0; r < 4; r++) { m_run[r] = -1e30f; ssum[r] = 0.f; }

  for (int jt = 0; jt < 32; jt++) {
    int j0 = jt * 64;
    f16 (*RsA)[72] = (jt & 1) ? Rs1 : Rs0;   // panel jt: n in [0,64)
    f16 (*RsB)[72] = (jt & 1) ? Rs0 : Rs1;   // panel jt-1: n in [64,128)
    {
      int row = tid >> 2, c0 = (tid & 3) * 16;
      const f16* kp = kb + ((size_t)bh * NSEQ + j0 + row) * 64 + c0;
      *(f16x8*)&KBs[row][c0]     = *(const f16x8*)kp;
      *(f16x8*)&KBs[row][c0 + 8] = *(const f16x8*)(kp + 8);
      // v2t rows: Vs[d][j] straight b128 copies (no transpose needed)
      const f16* vp = v2t + ((size_t)bh * 64 + row) * NSEQ + j0 + c0;
      *(f16x8*)&Vs[row][c0]     = *(const f16x8*)vp;
      *(f16x8*)&Vs[row][c0 + 8] = *(const f16x8*)(vp + 8);
      const f16* rp = relq + ((size_t)h * NPOS + base0 - 64*jt + row) * 64 + c0;
      *(f16x8*)&RsA[row][c0]     = *(const f16x8*)rp;
      *(f16x8*)&RsA[row][c0 + 8] = *(const f16x8*)(rp + 8);
    }
    __syncthreads();   // s1: staging visible
    f32x4 cacc[4];
    f16x8 ka0 = {}, ka1 = {};
    #pragma unroll
    for (int y = 0; y < 4; y++) {
      f16x8 b0 = *(const f16x8*)&KBs[16*y + lc][8*lr];
      f16x8 b1 = *(const f16x8*)&KBs[16*y + lc][32 + 8*lr];
      f32x4 t = {};
      t = MFMA16(qa0, b0, t);
      t = MFMA16(qa1, b1, t);
      cacc[y] = t;
      if (y == w) { ka0 = b0; ka1 = b1; }
    }
    // G blocks: only g in [3-w, 7-w] ever contribute to this block's band
    #pragma unroll
    for (int gg = 0; gg < 5; gg++) {
      int g = 3 - w + gg;
      const f16* r0p = (g < 4) ? &RsA[16*g + lc][8*lr]      : &RsB[16*(g-4) + lc][8*lr];
      const f16* r1p = (g < 4) ? &RsA[16*g + lc][32 + 8*lr] : &RsB[16*(g-4) + lc][32 + 8*lr];
      f32x4 ga = {};
      ga = MFMA16(ka0, *(const f16x8*)r0p, ga);
      ga = MFMA16(ka1, *(const f16x8*)r1p, ga);
      int jj = 16*w + 4*lr;
      #pragma unroll
      for (int r = 0; r < 4; r++) {
        int ii = 16*g + lc + jj + r - 63;   // i = n + j - 63
        if ((unsigned)ii < 64u) G2[jj + r][ii] = (f16)ga[r];
      }
    }
    __syncthreads();   // s2: G2 complete; KBs frag reads done -> Pw overlay safe
    float l[4][4];
    #pragma unroll
    for (int y = 0; y < 4; y++) {
      f16x4 gv = *(const f16x4*)&G2[16*y + lc][16*w + 4*lr];
      #pragma unroll
      for (int r = 0; r < 4; r++) l[y][r] = cacc[y][r] + (float)gv[r];
    }
    #pragma unroll
    for (int r = 0; r < 4; r++) {
      float tm = fmaxf(fmaxf(l[0][r], l[1][r]), fmaxf(l[2][r], l[3][r]));
      #pragma unroll
      for (int mk = 1; mk <= 8; mk <<= 1) tm = fmaxf(tm, __shfl_xor(tm, mk));
      if (tm > m_run[r]) {
        float sc = __expf(m_run[r] - tm);
        ssum[r] *= sc;
        #pragma unroll
        for (int nt = 0; nt < 4; nt++) o1a[nt][r] *= sc;
        m_run[r] = tm;
      }
      float mnew = m_run[r];
      float ps = 0.f;
      #pragma unroll
      for (int y = 0; y < 4; y++) {
        float p = __expf(l[y][r] - mnew);
        ps += p;
        Pw[4*lr + r][16*y + lc] = (f16)p;
      }
      ssum[r] += ps;
      // capture running max per tile in registers: lane lc owns jt=lc, 16+lc
      if (jt < 16) { if (lc == jt) mreg0[r] = mnew; }
      else         { if (lc == jt - 16) mreg1[r] = mnew; }
    }
    // no barrier: Pw is per-wave written & read (lgkmcnt orders within wave)
    {
      int prow = lane >> 2, pc0 = (lane & 3) * 16;
      f16* ap = attn + ((size_t)z * NSEQ + i0 + 16*w + prow) * NSEQ + j0 + pc0;
      *(f16x8*)ap       = *(const f16x8*)&Pw[prow][pc0];
      *(f16x8*)(ap + 8) = *(const f16x8*)&Pw[prow][pc0 + 8];
    }
    {
      f16x8 pa0 = *(const f16x8*)&Pw[lc][8*lr];
      f16x8 pa1 = *(const f16x8*)&Pw[lc][32 + 8*lr];
      #pragma unroll
      for (int nt = 0; nt < 4; nt++) {
        f16x8 vf0 = *(const f16x8*)&Vs[16*nt + lc][8*lr];
        f16x8 vf1 = *(const f16x8*)&Vs[16*nt + lc][32 + 8*lr];
        o1a[nt] = MFMA16(pa0, vf0, o1a[nt]);
        o1a[nt] = MFMA16(pa1, vf1, o1a[nt]);
      }
    }
    __syncthreads();   // s3: all reads of KBs/Pw/G2/Vs/Rs done -> restage ok
  }
  // epilogue: reduce s per row; write fac (for pv2) and out1
  float invs[4];
  #pragma unroll
  for (int r = 0; r < 4; r++) {
    float s = ssum[r];
    #pragma unroll
    for (int mk = 1; mk <= 8; mk <<= 1) s += __shfl_xor(s, mk);
    invs[r] = 1.f / s;
    int il = 16*w + 4*lr + r;
    float mf = m_run[r];
    #pragma unroll
    for (int jtb = 0; jtb < 2; jtb++) {
      int jt = jtb * 16 + lc;
      float mv = (jtb == 0) ? mreg0[r] : mreg1[r];
      float fv = __expf(mv - mf) * invs[r];
      fac[((size_t)z * NSEQ + i0 + il) * 32 + jt] = fv;
    }
  }
  #pragma unroll
  for (int nt = 0; nt < 4; nt++)
    #pragma unroll
    for (int r = 0; r < 4; r++) {
      int row = i0 + 16*w + 4*lr + r;
      o1acc[((size_t)b * NSEQ + row) * 512 + h * 64 + 16*nt + lc] = (f16)(o1a[nt][r] * invs[r]);
    }
}

// ---------------- pv2: out2[j,d] = sum_i (fac[i][jt] P[i,j]) v1[i,d] ----------------
__global__ __launch_bounds__(256) void pv2_k(const f16* __restrict__ attn,
    const f16* __restrict__ v1t, const float* __restrict__ fac,
    f16* __restrict__ oacc, int bh0)
{
  __shared__ f16 As[64][56];   // P^T: [j][k=i]
  __shared__ f16 Vs[64][56];   // v1t rows: [d][k=i]
  int z = blockIdx.y, bh = bh0 + z, b = bh >> 3, h = bh & 7;
  int r0 = blockIdx.x * 64;
  int tid = threadIdx.x, w = tid >> 6, lane = tid & 63;
  int lr = lane >> 4, lc = lane & 15;
  f32x4 acc[4] = {};
  for (int k0 = 0; k0 < NSEQ; k0 += 32) {
    {
      int kk = tid >> 3, c0 = (tid & 7) * 8;
      f16x8 av = *(const f16x8*)&attn[((size_t)z * NSEQ + k0 + kk) * NSEQ + r0 + c0];
      f16 sc = (f16)fac[((size_t)z * NSEQ + k0 + kk) * 32 + (r0 >> 6)];
      #pragma unroll
      for (int tt = 0; tt < 8; tt++) { int t = (tt + kk) & 7; As[c0 + t][kk] = av[t] * sc; }
      int row = tid >> 2, cv = (tid & 3) * 8;
      *(f16x8*)&Vs[row][cv] =
          *(const f16x8*)&v1t[((size_t)bh * 64 + row) * NSEQ + k0 + cv];
    }
    __syncthreads();
    f16x8 af = *(const f16x8*)&As[16*w + lc][8*lr];
    #pragma unroll
    for (int nt = 0; nt < 4; nt++) {
      f16x8 vf = *(const f16x8*)&Vs[16*nt + lc][8*lr];
      acc[nt] = MFMA16(af, vf, acc[nt]);
    }
    __syncthreads();
  }
  #pragma unroll
  for (int nt = 0; nt < 4; nt++)
    #pragma unroll
    for (int r = 0; r < 4; r++) {
      int row = r0 + 16*w + 4*lr + r;
      oacc[((size_t)b * NSEQ + row) * 512 + h * 64 + 16*nt + lc] = (f16)acc[nt][r];
    }
}

extern "C" void kernel_launch(void* const* d_in, const int* in_sizes, int n_in,
                              void* d_out, int out_size, void* d_ws, size_t ws_size,
                              hipStream_t stream) {
  const float* x1   = (const float*)d_in[0];
  const float* x2   = (const float*)d_in[1];
  const float* Wq   = (const float*)d_in[2];
  const float* Wk   = (const float*)d_in[3];
  const float* Wv1  = (const float*)d_in[4];
  const float* Wv2  = (const float*)d_in[5];
  const float* Wrel = (const float*)d_in[6];
  const float* rpb  = (const float*)d_in[7];
  const float* Wo1  = (const float*)d_in[8];
  const float* bo1  = (const float*)d_in[9];
  const float* Wo2  = (const float*)d_in[10];
  const float* bo2  = (const float*)d_in[11];
  float* out = (float*)d_out;

  char* base = (char*)d_ws;
  size_t off = 0;
  auto alloc = [&](size_t bytes) -> void* {
    void* p = base + off; off += (bytes + 255) & ~(size_t)255; return p;
  };
  float* pos   = (float*)alloc((size_t)NPOS * 192 * 4);
  f16*   relq  = (f16*)  alloc((size_t)NH * NPOS * 64 * 2);
  f16*   qh    = (f16*)  alloc((size_t)16 * NSEQ * 64 * 2);
  f16*   kbh   = (f16*)  alloc((size_t)16 * NSEQ * 64 * 2);
  f16*   v1t   = (f16*)  alloc((size_t)16 * 64 * NSEQ * 2);
  f16*   v2t   = (f16*)  alloc((size_t)16 * 64 * NSEQ * 2);
  f16*   o1acc = (f16*)  alloc((size_t)2 * NSEQ * 512 * 2);
  f16*   o2acc = (f16*)  alloc((size_t)2 * NSEQ * 512 * 2);
  size_t baseB = off;

  int chunk = 1;
  for (int c = 16; c >= 1; c >>= 1) {
    size_t needB = baseB + (size_t)c * (NSEQ * (size_t)NSEQ * 2 + NSEQ * 32 * 4);
    if (needB <= ws_size) { chunk = c; break; }
  }
  f16*   attn = (f16*)(base + baseB);
  float* fac  = (float*)(base + baseB + (size_t)chunk * NSEQ * NSEQ * 2);

  pos_embed_k<<<(NPOS + 7) / 8, 256, 0, stream>>>(pos);
  relq_k<<<dim3(8, 64), 256, 0, stream>>>(pos, Wrel, relq);
  projx_k<1024, false><<<dim3(16, 64), 256, 0, stream>>>(x1, Wq, Wv1, qh, v1t, nullptr);
  projx_k<512,  true ><<<dim3(16, 64), 256, 0, stream>>>(x2, Wk, Wv2, kbh, v2t, rpb);

  for (int bh0 = 0; bh0 < 16; bh0 += chunk) {
    attn_k<<<dim3(32, chunk), 256, 0, stream>>>(qh, kbh, relq, v2t, attn, fac, o1acc, bh0);
    pv2_k<<<dim3(32, chunk), 256, 0, stream>>>(attn, v1t, fac, o2acc, bh0);
  }

  outproj_k<<<dim3(16, 128), 256, 0, stream>>>(o1acc, o2acc, Wo1, Wo2, bo1, bo2, out);
}

// Round 9
// 308.155 us; speedup vs baseline: 1.3873x; 1.1125x over previous
//
#include <hip/hip_runtime.h>
#include <math.h>

#define NSEQ 2048
#define NPOS 4095   // 2*NSEQ-1
#define NH   8

typedef _Float16 f16;
typedef f16 f16x8 __attribute__((ext_vector_type(8)));
typedef f16 f16x4 __attribute__((ext_vector_type(4)));
typedef float f32x4 __attribute__((ext_vector_type(4)));

#define MFMA16(a,b,c) __builtin_amdgcn_mfma_f32_16x16x32_f16(a,b,c,0,0,0)

__device__ __forceinline__ f16x8 cvt8(float4 a, float4 b) {
  f16x8 r = {(f16)a.x, (f16)a.y, (f16)a.z, (f16)a.w,
             (f16)b.x, (f16)b.y, (f16)b.z, (f16)b.w};
  return r;
}
__device__ __forceinline__ f16x8 scale8(f16x8 v, float4 a, float4 b) {
  f16x8 r;
  r[0] = (f16)((float)v[0] * a.x); r[1] = (f16)((float)v[1] * a.y);
  r[2] = (f16)((float)v[2] * a.z); r[3] = (f16)((float)v[3] * a.w);
  r[4] = (f16)((float)v[4] * b.x); r[5] = (f16)((float)v[5] * b.y);
  r[6] = (f16)((float)v[6] * b.z); r[7] = (f16)((float)v[7] * b.w);
  return r;
}

// ---------------- positional embedding pos[NPOS][192], one lane per (t,f) ----
__global__ __launch_bounds__(256) void pos_embed_k(float* __restrict__ pos) {
  int t = blockIdx.x * 8 + (threadIdx.x >> 5);
  int f = threadIdx.x & 31;
  if (t >= NPOS) return;
  float dist = (float)(t - (NSEQ - 1));
  float ad = fabsf(dist);
  float sgn = (dist > 0.f) ? 1.f : ((dist < 0.f) ? -1.f : 0.f);
  double mean = 64.0 * (double)(f + 1);       // linspace(64,2048,32)
  double conc = (mean / 32.0) * (mean / 32.0);
  double rate = mean / 1024.0;
  double p = 0.0;
  if (ad > 0.f) {
    double lu = (conc - 1.0) * log((double)ad) - rate * (double)ad;
    double ln = lgamma(conc) - conc * log(rate);
    p = exp(lu - ln);
  }
  float pf = (float)p + 1e-8f;
  float gmax = pf;
  #pragma unroll
  for (int mk = 1; mk <= 16; mk <<= 1) gmax = fmaxf(gmax, __shfl_xor(gmax, mk));
  float fg = pf / gmax;
  float hl = exp2f(3.f + 8.f * (float)f * (1.f / 31.f));
  float fe = exp2f(-ad / hl);
  float cw = exp2f((float)(f + 1)) - 1.f;
  float fc = (cw > ad) ? 1.f : 0.f;
  float* row = pos + (size_t)t * 192;
  row[f]       = fe;       row[32 + f]  = fc;       row[64 + f]  = fg;
  row[96 + f]  = sgn * fe; row[128 + f] = sgn * fc; row[160 + f] = sgn * fg;
}

// ---------------- relq = pos @ Wrel -> f16 [h][NPOS][64] (64x64 tiles) ------
__global__ __launch_bounds__(256) void relq_k(
    const float* __restrict__ A, const float* __restrict__ W, f16* __restrict__ relq)
{
  __shared__ f16 As[64][56];
  __shared__ f16 Bs[64][56];
  int tid = threadIdx.x, w = tid >> 6, lane = tid & 63, lr = lane >> 4, lc = lane & 15;
  int m0 = blockIdx.y * 64, n0 = blockIdx.x * 64;
  int ar = tid >> 2, ac = (tid & 3) * 8;
  int bk = tid >> 3, bn = (tid & 7) * 8;
  f32x4 acc[4] = {};
  for (int k0 = 0; k0 < 192; k0 += 32) {
    float4 a0 = make_float4(0.f,0.f,0.f,0.f), a1 = a0;
    if (m0 + ar < NPOS) {
      const float* ap = &A[(size_t)(m0 + ar) * 192 + k0 + ac];
      a0 = *(const float4*)ap; a1 = *(const float4*)(ap + 4);
    }
    *(f16x8*)&As[ar][ac] = cvt8(a0, a1);
    const float* bp = &W[(size_t)(k0 + bk) * 512 + n0 + bn];
    float4 b0 = *(const float4*)bp, b1 = *(const float4*)(bp + 4);
    f16 bv[8] = {(f16)b0.x,(f16)b0.y,(f16)b0.z,(f16)b0.w,(f16)b1.x,(f16)b1.y,(f16)b1.z,(f16)b1.w};
    #pragma unroll
    for (int tt = 0; tt < 8; tt++) { int t = (tt + bk) & 7; Bs[bn + t][bk] = bv[t]; }
    __syncthreads();
    f16x8 af = *(const f16x8*)&As[16*w + lc][8*lr];
    #pragma unroll
    for (int nt = 0; nt < 4; nt++) {
      f16x8 bf = *(const f16x8*)&Bs[16*nt + lc][8*lr];
      acc[nt] = MFMA16(af, bf, acc[nt]);
    }
    __syncthreads();
  }
  #pragma unroll
  for (int nt = 0; nt < 4; nt++)
    #pragma unroll
    for (int r = 0; r < 4; r++) {
      int m = m0 + 16*w + 4*lr + r;
      if (m >= NPOS) continue;
      int nn = n0 + 16*nt + lc;
      relq[((size_t)(nn >> 6) * NPOS + m) * 64 + (nn & 63)] = (f16)acc[nt][r];
    }
}

// ---------------- input projections (64x64 tile): A[4096,KD] x (W1|W2) -----
// first half  -> O1 normal head-split [bh][row][64] (optionally *0.125+rpb)
// second half -> O2t TRANSPOSED [bh][d][2048] (f16x4-packed stores)
template<int KD, bool SC1>
__global__ __launch_bounds__(256) void projx_k(
    const float* __restrict__ A, const float* __restrict__ W1, const float* __restrict__ W2,
    f16* __restrict__ O1, f16* __restrict__ O2t, const float* __restrict__ rpb)
{
  __shared__ f16 As[64][56];
  __shared__ f16 Bs[64][56];
  int tid = threadIdx.x, w = tid >> 6, lane = tid & 63, lr = lane >> 4, lc = lane & 15;
  int m0 = blockIdx.y * 64, n0g = blockIdx.x * 64;
  bool first = (n0g < 512);
  const float* W = first ? W1 : W2;
  int n0 = n0g & 511;
  int ar = tid >> 2, ac = (tid & 3) * 8;
  int bk = tid >> 3, bn = (tid & 7) * 8;
  f32x4 acc[4] = {};
  for (int k0 = 0; k0 < KD; k0 += 32) {
    const float* ap = &A[(size_t)(m0 + ar) * KD + k0 + ac];
    *(f16x8*)&As[ar][ac] = cvt8(*(const float4*)ap, *(const float4*)(ap + 4));
    const float* bp = &W[(size_t)(k0 + bk) * 512 + n0 + bn];
    float4 b0 = *(const float4*)bp, b1 = *(const float4*)(bp + 4);
    f16 bv[8] = {(f16)b0.x,(f16)b0.y,(f16)b0.z,(f16)b0.w,(f16)b1.x,(f16)b1.y,(f16)b1.z,(f16)b1.w};
    #pragma unroll
    for (int tt = 0; tt < 8; tt++) { int t = (tt + bk) & 7; Bs[bn + t][bk] = bv[t]; }
    __syncthreads();
    f16x8 af = *(const f16x8*)&As[16*w + lc][8*lr];
    #pragma unroll
    for (int nt = 0; nt < 4; nt++) {
      f16x8 bf = *(const f16x8*)&Bs[16*nt + lc][8*lr];
      acc[nt] = MFMA16(af, bf, acc[nt]);
    }
    __syncthreads();
  }
  if (first) {
    #pragma unroll
    for (int nt = 0; nt < 4; nt++)
      #pragma unroll
      for (int r = 0; r < 4; r++) {
        int m = m0 + 16*w + 4*lr + r;
        int nn = n0 + 16*nt + lc;
        float vv = acc[nt][r];
        if (SC1) vv = vv * 0.125f + rpb[nn];
        O1[(((size_t)((m >> 11) * NH + (nn >> 6))) * NSEQ + (m & (NSEQ - 1))) * 64 + (nn & 63)] = (f16)vv;
      }
  } else {
    int mb = m0 + 16*w + 4*lr;
    #pragma unroll
    for (int nt = 0; nt < 4; nt++) {
      int nn = n0 + 16*nt + lc;
      f16x4 pk = {(f16)acc[nt][0], (f16)acc[nt][1], (f16)acc[nt][2], (f16)acc[nt][3]};
      *(f16x4*)&O2t[(((size_t)((mb >> 11) * NH + (nn >> 6))) * 64 + (nn & 63)) * NSEQ + (mb & (NSEQ - 1))] = pk;
    }
  }
}

// ---------------- fused output projections (64x64 tile) ----------------
__global__ __launch_bounds__(256) void outproj_k(
    const f16* __restrict__ o1, const f16* __restrict__ o2,
    const float* __restrict__ Wo1, const float* __restrict__ Wo2,
    const float* __restrict__ bo1, const float* __restrict__ bo2,
    float* __restrict__ out)
{
  __shared__ f16 As[64][56];
  __shared__ f16 Bs[64][56];
  int by = blockIdx.y;
  bool first = (by < 64);
  const f16* A = first ? o1 : o2;
  const float* W = first ? Wo1 : Wo2;
  const float* bias = first ? bo1 : bo2;
  float* O = out + (first ? 0 : (size_t)4096 * 1024);
  int tid = threadIdx.x, w = tid >> 6, lane = tid & 63, lr = lane >> 4, lc = lane & 15;
  int m0 = (by & 63) * 64, n0 = blockIdx.x * 64;
  int ar = tid >> 2, ac = (tid & 3) * 8;
  int bk = tid >> 3, bn = (tid & 7) * 8;
  f32x4 acc[4] = {};
  for (int k0 = 0; k0 < 512; k0 += 32) {
    *(f16x8*)&As[ar][ac] = *(const f16x8*)&A[(size_t)(m0 + ar) * 512 + k0 + ac];
    const float* bp = &W[(size_t)(k0 + bk) * 1024 + n0 + bn];
    float4 b0 = *(const float4*)bp, b1 = *(const float4*)(bp + 4);
    f16 bv[8] = {(f16)b0.x,(f16)b0.y,(f16)b0.z,(f16)b0.w,(f16)b1.x,(f16)b1.y,(f16)b1.z,(f16)b1.w};
    #pragma unroll
    for (int tt = 0; tt < 8; tt++) { int t = (tt + bk) & 7; Bs[bn + t][bk] = bv[t]; }
    __syncthreads();
    f16x8 af = *(const f16x8*)&As[16*w + lc][8*lr];
    #pragma unroll
    for (int nt = 0; nt < 4; nt++) {
      f16x8 bf = *(const f16x8*)&Bs[16*nt + lc][8*lr];
      acc[nt] = MFMA16(af, bf, acc[nt]);
    }
    __syncthreads();
  }
  #pragma unroll
  for (int nt = 0; nt < 4; nt++)
    #pragma unroll
    for (int r = 0; r < 4; r++) {
      int m = m0 + 16*w + 4*lr + r;
      int n = n0 + 16*nt + lc;
      O[(size_t)m * 1024 + n] = acc[nt][r] + bias[n];
    }
}

// ---------------- fused logits + online softmax + out1 PV ----------------
// l[i,j] = q[i]·kb[j] + G[j, i-j+63];  G[j,n] = kb[j]·relq[nbase+n]
// Writes P TRANSPOSED (attnT[j][i], f16x4 direct from regs) and fac_t[jt][i].
// R ring + g-pruning + per-reg tile-max as round 8; kb/v2t/R prefetched into
// registers mid-tile (T14 split) and written to LDS after the end barrier.
// LDS (46080 B): Qs[64][72]@0 (G2[64][68] overlay), KBs[64][72]@9216 (Pw
// per-wave [16][72] overlay), Rs0/Rs1[64][72]@18432/27648, Vs[64][72]@36864.
__global__ __launch_bounds__(256) void attn_k(
    const f16* __restrict__ q, const f16* __restrict__ kb,
    const f16* __restrict__ relq, const f16* __restrict__ v2t,
    f16* __restrict__ attnT, float* __restrict__ fac_t,
    f16* __restrict__ o1acc, int bh0)
{
  __shared__ char smem[46080];
  f16 (*Qs)[72]  = (f16(*)[72])smem;
  f16 (*KBs)[72] = (f16(*)[72])(smem + 9216);
  f16 (*Rs0)[72] = (f16(*)[72])(smem + 18432);
  f16 (*Rs1)[72] = (f16(*)[72])(smem + 27648);
  f16 (*Vs)[72]  = (f16(*)[72])(smem + 36864);   // [d][j] from v2t
  f16 (*G2)[68]  = (f16(*)[68])smem;             // overlay Qs
  int z = blockIdx.y, bh = bh0 + z, b = bh >> 3, h = bh & 7;
  int i0 = blockIdx.x * 64;
  int tid = threadIdx.x, w = tid >> 6, lane = tid & 63;
  int lr = lane >> 4, lc = lane & 15;
  f16 (*Pw)[72] = (f16(*)[72])(smem + 9216 + w * 2304);  // per-wave [16][72]
  int base0 = i0 + 1984;   // (NSEQ-1) + i0 - 63
  int row = tid >> 2, c0 = (tid & 3) * 16;

  {
    const f16* qp = q + ((size_t)bh * NSEQ + i0 + row) * 64 + c0;
    *(f16x8*)&Qs[row][c0]     = *(const f16x8*)qp;
    *(f16x8*)&Qs[row][c0 + 8] = *(const f16x8*)(qp + 8);
    // prologue: panel -1 -> Rs1
    const f16* rp = relq + ((size_t)h * NPOS + base0 + 64 + row) * 64 + c0;
    *(f16x8*)&Rs1[row][c0]     = *(const f16x8*)rp;
    *(f16x8*)&Rs1[row][c0 + 8] = *(const f16x8*)(rp + 8);
  }
  __syncthreads();
  f16x8 qa0 = *(const f16x8*)&Qs[16*w + lc][8*lr];
  f16x8 qa1 = *(const f16x8*)&Qs[16*w + lc][32 + 8*lr];

  // tile-0 staged registers
  const f16* kpb = kb  + ((size_t)bh * NSEQ + row) * 64 + c0;
  const f16* vpb = v2t + ((size_t)bh * 64 + row) * NSEQ + c0;
  const f16* rpb0 = relq + ((size_t)h * NPOS + base0 + row) * 64 + c0;
  f16x8 skb0 = *(const f16x8*)kpb,  skb1 = *(const f16x8*)(kpb + 8);
  f16x8 sv0  = *(const f16x8*)vpb,  sv1  = *(const f16x8*)(vpb + 8);
  f16x8 sr0  = *(const f16x8*)rpb0, sr1  = *(const f16x8*)(rpb0 + 8);

  float m_run[4], ssum[4];
  float mreg0[4] = {}, mreg1[4] = {};
  f32x4 o1a[4] = {};
  #pragma unroll
  for (int r = 0; r < 4; r++) { m_run[r] = -1e30f; ssum[r] = 0.f; }

  for (int jt = 0; jt < 32; jt++) {
    int j0 = jt * 64;
    f16 (*RsA)[72] = (jt & 1) ? Rs1 : Rs0;   // panel jt: n in [0,64)
    f16 (*RsB)[72] = (jt & 1) ? Rs0 : Rs1;   // panel jt-1: n in [64,128)
    // write prefetched registers to LDS
    *(f16x8*)&KBs[row][c0]     = skb0;  *(f16x8*)&KBs[row][c0 + 8] = skb1;
    *(f16x8*)&Vs[row][c0]      = sv0;   *(f16x8*)&Vs[row][c0 + 8]  = sv1;
    *(f16x8*)&RsA[row][c0]     = sr0;   *(f16x8*)&RsA[row][c0 + 8] = sr1;
    __syncthreads();   // s1: staging visible
    f32x4 cacc[4];
    f16x8 ka0 = {}, ka1 = {};
    #pragma unroll
    for (int y = 0; y < 4; y++) {
      f16x8 b0 = *(const f16x8*)&KBs[16*y + lc][8*lr];
      f16x8 b1 = *(const f16x8*)&KBs[16*y + lc][32 + 8*lr];
      f32x4 t = {};
      t = MFMA16(qa0, b0, t);
      t = MFMA16(qa1, b1, t);
      cacc[y] = t;
      if (y == w) { ka0 = b0; ka1 = b1; }
    }
    // G blocks: only g in [3-w, 7-w] ever contribute to this block's band
    #pragma unroll
    for (int gg = 0; gg < 5; gg++) {
      int g = 3 - w + gg;
      const f16* r0p = (g < 4) ? &RsA[16*g + lc][8*lr]      : &RsB[16*(g-4) + lc][8*lr];
      const f16* r1p = (g < 4) ? &RsA[16*g + lc][32 + 8*lr] : &RsB[16*(g-4) + lc][32 + 8*lr];
      f32x4 ga = {};
      ga = MFMA16(ka0, *(const f16x8*)r0p, ga);
      ga = MFMA16(ka1, *(const f16x8*)r1p, ga);
      int jj = 16*w + 4*lr;
      #pragma unroll
      for (int r = 0; r < 4; r++) {
        int ii = 16*g + lc + jj + r - 63;   // i = n + j - 63
        if ((unsigned)ii < 64u) G2[jj + r][ii] = (f16)ga[r];
      }
    }
    // prefetch next tile into registers (latency hides under softmax+PV)
    {
      int jn = (jt < 31) ? jt + 1 : 31;
      const f16* kpn = kb  + ((size_t)bh * NSEQ + jn * 64 + row) * 64 + c0;
      const f16* vpn = v2t + ((size_t)bh * 64 + row) * NSEQ + jn * 64 + c0;
      const f16* rpn = relq + ((size_t)h * NPOS + base0 - 64 * jn + row) * 64 + c0;
      skb0 = *(const f16x8*)kpn;  skb1 = *(const f16x8*)(kpn + 8);
      sv0  = *(const f16x8*)vpn;  sv1  = *(const f16x8*)(vpn + 8);
      sr0  = *(const f16x8*)rpn;  sr1  = *(const f16x8*)(rpn + 8);
    }
    __syncthreads();   // s2: G2 complete; KBs frag reads done -> Pw overlay safe
    float l[4][4];
    #pragma unroll
    for (int y = 0; y < 4; y++) {
      f16x4 gv = *(const f16x4*)&G2[16*y + lc][16*w + 4*lr];
      #pragma unroll
      for (int r = 0; r < 4; r++) l[y][r] = cacc[y][r] + (float)gv[r];
    }
    float pvr[4][4];   // [r][y]
    #pragma unroll
    for (int r = 0; r < 4; r++) {
      float tm = fmaxf(fmaxf(l[0][r], l[1][r]), fmaxf(l[2][r], l[3][r]));
      #pragma unroll
      for (int mk = 1; mk <= 8; mk <<= 1) tm = fmaxf(tm, __shfl_xor(tm, mk));
      if (tm > m_run[r]) {
        float sc = __expf(m_run[r] - tm);
        ssum[r] *= sc;
        #pragma unroll
        for (int nt = 0; nt < 4; nt++) o1a[nt][r] *= sc;
        m_run[r] = tm;
      }
      float mnew = m_run[r];
      float ps = 0.f;
      #pragma unroll
      for (int y = 0; y < 4; y++) {
        float p = __expf(l[y][r] - mnew);
        ps += p;
        pvr[r][y] = p;
        Pw[4*lr + r][16*y + lc] = (f16)p;
      }
      ssum[r] += ps;
      // capture running max per tile in registers: lane lc owns jt=lc, 16+lc
      if (jt < 16) { if (lc == jt) mreg0[r] = mnew; }
      else         { if (lc == jt - 16) mreg1[r] = mnew; }
    }
    // transposed P store, direct from registers: attnT[j][i]
    #pragma unroll
    for (int y = 0; y < 4; y++) {
      f16x4 pk = {(f16)pvr[0][y], (f16)pvr[1][y], (f16)pvr[2][y], (f16)pvr[3][y]};
      *(f16x4*)&attnT[((size_t)z * NSEQ + j0 + 16*y + lc) * NSEQ + i0 + 16*w + 4*lr] = pk;
    }
    // out1 PV: o1a += P(own 16 rows) x v2-tile  (Pw per-wave, lgkmcnt-ordered)
    {
      f16x8 pa0 = *(const f16x8*)&Pw[lc][8*lr];
      f16x8 pa1 = *(const f16x8*)&Pw[lc][32 + 8*lr];
      #pragma unroll
      for (int nt = 0; nt < 4; nt++) {
        f16x8 vf0 = *(const f16x8*)&Vs[16*nt + lc][8*lr];
        f16x8 vf1 = *(const f16x8*)&Vs[16*nt + lc][32 + 8*lr];
        o1a[nt] = MFMA16(pa0, vf0, o1a[nt]);
        o1a[nt] = MFMA16(pa1, vf1, o1a[nt]);
      }
    }
    __syncthreads();   // s3: all reads of KBs/Pw/G2/Vs/Rs done -> restage ok
  }
  // epilogue: reduce s per row; write fac_t (for pv2) and out1
  float invs[4];
  #pragma unroll
  for (int r = 0; r < 4; r++) {
    float s = ssum[r];
    #pragma unroll
    for (int mk = 1; mk <= 8; mk <<= 1) s += __shfl_xor(s, mk);
    invs[r] = 1.f / s;
    int il = 16*w + 4*lr + r;
    float mf = m_run[r];
    #pragma unroll
    for (int jtb = 0; jtb < 2; jtb++) {
      int jt = jtb * 16 + lc;
      float mv = (jtb == 0) ? mreg0[r] : mreg1[r];
      float fv = __expf(mv - mf) * invs[r];
      fac_t[((size_t)z * 32 + jt) * NSEQ + i0 + il] = fv;
    }
  }
  #pragma unroll
  for (int nt = 0; nt < 4; nt++)
    #pragma unroll
    for (int r = 0; r < 4; r++) {
      int rw = i0 + 16*w + 4*lr + r;
      o1acc[((size_t)b * NSEQ + rw) * 512 + h * 64 + 16*nt + lc] = (f16)(o1a[nt][r] * invs[r]);
    }
}

// ---------------- pv2: out2[j,d] = sum_i attnT[j,i]*fac_t[jt0,i]*v1[i,d] ----
// A-fragments straight from global attnT (no LDS); Vs = v1t rows scaled by
// fac_t at staging (all b128, conflict-free).
__global__ __launch_bounds__(256) void pv2_k(const f16* __restrict__ attnT,
    const f16* __restrict__ v1t, const float* __restrict__ fac_t,
    f16* __restrict__ oacc, int bh0)
{
  __shared__ f16 Vs[64][72];   // [d][k=i], 64-wide k tile
  int z = blockIdx.y, bh = bh0 + z, b = bh >> 3, h = bh & 7;
  int r0 = blockIdx.x * 64;    // j-block
  int tid = threadIdx.x, w = tid >> 6, lane = tid & 63;
  int lr = lane >> 4, lc = lane & 15;
  int row = tid >> 2, cv = (tid & 3) * 16;
  const f16* vp = v1t + ((size_t)bh * 64 + row) * NSEQ + cv;
  const float* fp = fac_t + ((size_t)z * 32 + blockIdx.x) * NSEQ + cv;
  const f16* ap = attnT + ((size_t)z * NSEQ + r0 + 16*w + lc) * NSEQ + 8*lr;
  f32x4 acc[4] = {};
  for (int k0 = 0; k0 < NSEQ; k0 += 64) {
    f16x8 v0 = *(const f16x8*)(vp + k0);
    f16x8 v1 = *(const f16x8*)(vp + k0 + 8);
    float4 f0 = *(const float4*)(fp + k0),     f1 = *(const float4*)(fp + k0 + 4);
    float4 f2 = *(const float4*)(fp + k0 + 8), f3 = *(const float4*)(fp + k0 + 12);
    *(f16x8*)&Vs[row][cv]     = scale8(v0, f0, f1);
    *(f16x8*)&Vs[row][cv + 8] = scale8(v1, f2, f3);
    __syncthreads();
    f16x8 a0 = *(const f16x8*)(ap + k0);
    f16x8 a1 = *(const f16x8*)(ap + k0 + 32);
    #pragma unroll
    for (int nt = 0; nt < 4; nt++) {
      acc[nt] = MFMA16(a0, *(const f16x8*)&Vs[16*nt + lc][8*lr], acc[nt]);
      acc[nt] = MFMA16(a1, *(const f16x8*)&Vs[16*nt + lc][32 + 8*lr], acc[nt]);
    }
    __syncthreads();
  }
  #pragma unroll
  for (int nt = 0; nt < 4; nt++)
    #pragma unroll
    for (int r = 0; r < 4; r++) {
      int rw = r0 + 16*w + 4*lr + r;
      oacc[((size_t)b * NSEQ + rw) * 512 + h * 64 + 16*nt + lc] = (f16)acc[nt][r];
    }
}

extern "C" void kernel_launch(void* const* d_in, const int* in_sizes, int n_in,
                              void* d_out, int out_size, void* d_ws, size_t ws_size,
                              hipStream_t stream) {
  const float* x1   = (const float*)d_in[0];
  const float* x2   = (const float*)d_in[1];
  const float* Wq   = (const float*)d_in[2];
  const float* Wk   = (const float*)d_in[3];
  const float* Wv1  = (const float*)d_in[4];
  const float* Wv2  = (const float*)d_in[5];
  const float* Wrel = (const float*)d_in[6];
  const float* rpb  = (const float*)d_in[7];
  const float* Wo1  = (const float*)d_in[8];
  const float* bo1  = (const float*)d_in[9];
  const float* Wo2  = (const float*)d_in[10];
  const float* bo2  = (const float*)d_in[11];
  float* out = (float*)d_out;

  char* base = (char*)d_ws;
  size_t off = 0;
  auto alloc = [&](size_t bytes) -> void* {
    void* p = base + off; off += (bytes + 255) & ~(size_t)255; return p;
  };
  float* pos   = (float*)alloc((size_t)NPOS * 192 * 4);
  f16*   relq  = (f16*)  alloc((size_t)NH * NPOS * 64 * 2);
  f16*   qh    = (f16*)  alloc((size_t)16 * NSEQ * 64 * 2);
  f16*   kbh   = (f16*)  alloc((size_t)16 * NSEQ * 64 * 2);
  f16*   v1t   = (f16*)  alloc((size_t)16 * 64 * NSEQ * 2);
  f16*   v2t   = (f16*)  alloc((size_t)16 * 64 * NSEQ * 2);
  f16*   o1acc = (f16*)  alloc((size_t)2 * NSEQ * 512 * 2);
  f16*   o2acc = (f16*)  alloc((size_t)2 * NSEQ * 512 * 2);
  size_t baseB = off;

  int chunk = 1;
  for (int c = 16; c >= 1; c >>= 1) {
    size_t needB = baseB + (size_t)c * (NSEQ * (size_t)NSEQ * 2 + NSEQ * 32 * 4);
    if (needB <= ws_size) { chunk = c; break; }
  }
  f16*   attnT = (f16*)(base + baseB);
  float* fac_t = (float*)(base + baseB + (size_t)chunk * NSEQ * NSEQ * 2);

  pos_embed_k<<<(NPOS + 7) / 8, 256, 0, stream>>>(pos);
  relq_k<<<dim3(8, 64), 256, 0, stream>>>(pos, Wrel, relq);
  projx_k<1024, false><<<dim3(16, 64), 256, 0, stream>>>(x1, Wq, Wv1, qh, v1t, nullptr);
  projx_k<512,  true ><<<dim3(16, 64), 256, 0, stream>>>(x2, Wk, Wv2, kbh, v2t, rpb);

  for (int bh0 = 0; bh0 < 16; bh0 += chunk) {
    attn_k<<<dim3(32, chunk), 256, 0, stream>>>(qh, kbh, relq, v2t, attnT, fac_t, o1acc, bh0);
    pv2_k<<<dim3(32, chunk), 256, 0, stream>>>(attnT, v1t, fac_t, o2acc, bh0);
  }

  outproj_k<<<dim3(16, 128), 256, 0, stream>>>(o1acc, o2acc, Wo1, Wo2, bo1, bo2, out);
}